// Round 12
// baseline (157.385 us; speedup 1.0000x reference)
//
#include <hip/hip_runtime.h>

#define Bn 64
#define Tn 512
#define Hn 768
#define Ln 21
#define EM_ELEMS (Bn*Tn*Ln)

// ws layout (floats)
#define DIFF_OFF 192

__device__ __forceinline__ float rl(float x, int i){
    return __int_as_float(__builtin_amdgcn_readlane(__float_as_int(x), i));
}

// 21 readlanes into 21 DISTINCT SGPRs in one asm block (pipelined, no SGPR reuse hazard)
// NOTE: loops containing this macro MUST stay rolled — 8x unrolling it miscompiled (r9/r10: inf).
#define READLANES(src, A) \
    asm volatile( \
        "v_readlane_b32 %0, %[v], 0\n\t" \
        "v_readlane_b32 %1, %[v], 1\n\t" \
        "v_readlane_b32 %2, %[v], 2\n\t" \
        "v_readlane_b32 %3, %[v], 3\n\t" \
        "v_readlane_b32 %4, %[v], 4\n\t" \
        "v_readlane_b32 %5, %[v], 5\n\t" \
        "v_readlane_b32 %6, %[v], 6\n\t" \
        "v_readlane_b32 %7, %[v], 7\n\t" \
        "v_readlane_b32 %8, %[v], 8\n\t" \
        "v_readlane_b32 %9, %[v], 9\n\t" \
        "v_readlane_b32 %10, %[v], 10\n\t" \
        "v_readlane_b32 %11, %[v], 11\n\t" \
        "v_readlane_b32 %12, %[v], 12\n\t" \
        "v_readlane_b32 %13, %[v], 13\n\t" \
        "v_readlane_b32 %14, %[v], 14\n\t" \
        "v_readlane_b32 %15, %[v], 15\n\t" \
        "v_readlane_b32 %16, %[v], 16\n\t" \
        "v_readlane_b32 %17, %[v], 17\n\t" \
        "v_readlane_b32 %18, %[v], 18\n\t" \
        "v_readlane_b32 %19, %[v], 19\n\t" \
        "v_readlane_b32 %20, %[v], 20\n\t" \
        : "=s"(A[0]),"=s"(A[1]),"=s"(A[2]),"=s"(A[3]),"=s"(A[4]), \
          "=s"(A[5]),"=s"(A[6]),"=s"(A[7]),"=s"(A[8]),"=s"(A[9]), \
          "=s"(A[10]),"=s"(A[11]),"=s"(A[12]),"=s"(A[13]),"=s"(A[14]), \
          "=s"(A[15]),"=s"(A[16]),"=s"(A[17]),"=s"(A[18]),"=s"(A[19]), \
          "=s"(A[20]) \
        : [v]"v"(src))

// ---------------- emissions = hidden @ W + b  (split-K x4, LDS combine) ----------------
__global__ __launch_bounds__(256) void emis_kernel(
    const float* __restrict__ hidden, const float* __restrict__ W,
    const float* __restrict__ bias, float* __restrict__ em)
{
    __shared__ float part[4][64][22];
    const int lane = threadIdx.x & 63;
    const int w    = threadIdx.x >> 6;
    const int row  = blockIdx.x*64 + lane;
    const int wb   = 64 + (lane < 20 ? lane : 19);
    const float4* h4 = (const float4*)(hidden + (size_t)row*Hn) + w*48;
    const float*  Wp = W + w*(192*Ln);
    float acc[Ln];
    #pragma unroll
    for (int j=0;j<Ln;++j) acc[j]=0.f;
    float4 hcur = h4[0];
    float Wa = Wp[lane], Wb2 = Wp[wb];
    for (int t=0;t<48;++t){
        float4 hn = hcur; float Wan = Wa, Wbn = Wb2;
        if (t<47){ hn = h4[t+1]; Wan = Wp[(t+1)*84+lane]; Wbn = Wp[(t+1)*84+wb]; }
        const float* hv = &hcur.x;
        #pragma unroll
        for (int c=0;c<4;++c){
            float x = hv[c];
            #pragma unroll
            for (int j=0;j<Ln;++j){
                const int idx = c*Ln+j;
                float wv = (idx<64) ? rl(Wa, idx) : rl(Wb2, idx-64);
                acc[j] = fmaf(x, wv, acc[j]);
            }
        }
        hcur=hn; Wa=Wan; Wb2=Wbn;
    }
    #pragma unroll
    for (int j=0;j<Ln;++j) part[w][lane][j] = acc[j];
    __syncthreads();
    float* ob = em + (size_t)blockIdx.x*64*Ln;
    for (int e=threadIdx.x; e<64*Ln; e+=256){
        int r = e/Ln, j = e-r*Ln;
        ob[e] = ((part[0][r][j]+part[1][r][j])+(part[2][r][j]+part[3][r][j])) + bias[j];
    }
}

// ---------------- fused: wave0 viterbi (publishes chunk progress), wave1 NLL,
//                  wave2 gold score then bp, waves2-7 bp ranges chase the producer ----------------
__global__ __launch_bounds__(512) void fused_kernel(
    const float* __restrict__ em, const int* __restrict__ labels,
    const int* __restrict__ amask, const float* __restrict__ st,
    const float* __restrict__ et, const float* __restrict__ trans,
    float* __restrict__ ws, float* __restrict__ logits)
{
    __shared__ float em_s[(Tn+2)*Ln];        // rows 512,513 duplicate row 511 (prefetch, no clamp)
    __shared__ float alpha_s[Tn*Ln];         // viterbi alpha stream
    __shared__ unsigned char hist_s[Tn*Ln];
    __shared__ int   lab2_s[Tn];             // attention mask
    __shared__ int   path_s[Tn];
    __shared__ unsigned char comp_s[64*Ln];
    __shared__ unsigned char ent_s[64];
    __shared__ float dump_s[64];
    __shared__ float logZ_s, score_s;
    __shared__ int   tag_s;
    __shared__ int   prog_s;                 // chunks of alpha complete (0..8)

    const int b    = blockIdx.x;
    const int tid  = threadIdx.x;
    const int wv   = tid >> 6;
    const int lane = tid & 63;
    const float* emb = em + (size_t)b*Tn*Ln;

    if (tid==0) prog_s = 0;
    for (int i=tid; i<Tn*Ln; i+=512) em_s[i] = emb[i];
    for (int i=tid; i<2*Ln; i+=512){
        int jj = (i < Ln) ? i : (i - Ln);
        em_s[Tn*Ln + i] = emb[(Tn-1)*Ln + jj];
    }
    lab2_s[tid] = amask[b*Tn + tid];
    __syncthreads();

    const bool act = (lane < Ln);
    const int  j   = act ? lane : 0;

    if (wv == 0){
        // ---- Viterbi forward (r7 core verbatim; alpha -> LDS; chunk progress published) ----
        const int* mk = amask + b*Tn;
        unsigned long long mb[8];
        #pragma unroll
        for (int c=0;c<8;++c) mb[c] = __ballot(mk[c*64 + lane] != 0);

        float trc[Ln];
        #pragma unroll
        for (int i=0;i<Ln;++i) trc[i] = trans[i*Ln + j];

        float sc = act ? (st[j] + em_s[j]) : -1e30f;
        float* sp = act ? (&alpha_s[j]) : (&dump_s[lane]);
        const int sstep = act ? Ln : 0;
        *sp = sc; sp += sstep;

        const float* ep = &em_s[Ln + j];
        float e1 = ep[0]; ep += Ln;       // t=1
        float e2 = ep[0]; ep += Ln;       // t=2; ep -> row 3

        #pragma unroll
        for (int c=0;c<8;++c){
            const unsigned long long m = mb[c];
            for (int tt = (c==0 ? 1 : 0); tt < 64; ++tt){
                float ec = e1; e1 = e2;
                e2 = ep[0]; ep += Ln;              // prefetch t+2 (rows extended)
                float A[21];
                READLANES(sc, A);
                float v0=A[0]+trc[0],  v1=A[1]+trc[1],  v2=A[2]+trc[2];
                float v3=A[3]+trc[3],  v4=A[4]+trc[4],  v5=A[5]+trc[5];
                float v6=A[6]+trc[6],  v7=A[7]+trc[7],  v8=A[8]+trc[8];
                float v9=A[9]+trc[9],  v10=A[10]+trc[10],v11=A[11]+trc[11];
                float v12=A[12]+trc[12],v13=A[13]+trc[13],v14=A[14]+trc[14];
                float v15=A[15]+trc[15],v16=A[16]+trc[16],v17=A[17]+trc[17];
                float v18=A[18]+trc[18],v19=A[19]+trc[19],v20=A[20]+trc[20];
                float a0 = fmaxf(fmaxf(v0,v1),v2);
                float a1 = fmaxf(fmaxf(v3,v4),v5);
                float a2 = fmaxf(fmaxf(v6,v7),v8);
                float a3 = fmaxf(fmaxf(v9,v10),v11);
                float a4 = fmaxf(fmaxf(v12,v13),v14);
                float a5 = fmaxf(fmaxf(v15,v16),v17);
                float a6 = fmaxf(fmaxf(v18,v19),v20);
                float b0 = fmaxf(fmaxf(a0,a1),a2);
                float b1 = fmaxf(fmaxf(a3,a4),a5);
                float best = fmaxf(fmaxf(b0,b1),a6);
                float scn = best + ec;
                int mc = (int)((m >> tt) & 1ull);
                sc = mc ? scn : sc;
                *sp = sc; sp += sstep;
            }
            if (lane==0){
                __threadfence_block();            // alpha writes drained before flag
                *(volatile int*)&prog_s = c+1;
            }
        }
        float val = act ? (sc + et[j]) : -1e30f;
        int   idx = act ? j : 1000;
        #pragma unroll
        for (int off=32; off>=1; off>>=1){
            float ov = __shfl_xor(val, off, 64);
            int   oi = __shfl_xor(idx, off, 64);
            if (ov > val || (ov==val && oi<idx)){ val=ov; idx=oi; }
        }
        if (lane==0) tag_s = idx;
    } else if (wv == 1){
        // ---- NLL forward in scaled-prob domain (r7 core verbatim) ----
        const int* lb = labels + b*Tn;
        unsigned long long mb[8];
        #pragma unroll
        for (int c=0;c<8;++c) mb[c] = __ballot(lb[c*64 + lane] != -100);

        float Ec[Ln];
        #pragma unroll
        for (int i=0;i<Ln;++i) Ec[i] = __expf(trans[i*Ln + j]);

        float p = act ? __expf(st[j] + em_s[j]) : 0.f;
        float M = 0.f;

        const float* ep = &em_s[Ln + j];
        float e1 = ep[0]; ep += Ln;
        float e2 = ep[0]; ep += Ln;

        #pragma unroll
        for (int c=0;c<8;++c){
            const unsigned long long m = mb[c];
            for (int tt = (c==0 ? 1 : 0); tt < 64; ++tt){
                float ec = e1; e1 = e2;
                e2 = ep[0]; ep += Ln;
                float pe = __expf(ec);
                float A[21];
                READLANES(p, A);
                float s0=0.f,s1=0.f,s2=0.f;
                #pragma unroll
                for (int i=0;i<Ln;++i){
                    if      (i%3==0) s0 = fmaf(A[i], Ec[i], s0);
                    else if (i%3==1) s1 = fmaf(A[i], Ec[i], s1);
                    else             s2 = fmaf(A[i], Ec[i], s2);
                }
                float pn = ((s0+s1)+s2) * pe;
                int lc = (int)((m >> tt) & 1ull);
                p = lc ? pn : p;
                if ((tt & 7) == 0){
                    float p0 = rl(p, 0);
                    int e; frexpf(p0, &e);
                    p = ldexpf(p, -e);
                    M += (float)e * 0.6931471805599453f;
                }
            }
        }
        float val = act ? (p * __expf(et[j])) : 0.f;
        #pragma unroll
        for (int off=32; off>=1; off>>=1) val += __shfl_xor(val, off, 64);
        if (lane==0) logZ_s = M + __logf(val);
    } else {
        // ---- wave2: gold score first (quick), then waves 2..7: bp ranges chasing producer ----
        if (wv == 2){
            const int* lb = labels + b*Tn;
            float term = 0.f; int cnt = 0;
            #pragma unroll
            for (int k=0;k<8;++k){
                int t = lane + 64*k;
                int labt = lb[t];
                if (t==0 || labt != -100) cnt++;
                if (t>=1 && labt != -100){
                    int lp = lb[t-1]; if (lp<0) lp=0;
                    term += trans[lp*Ln+labt] + em_s[t*Ln+labt];
                }
            }
            #pragma unroll
            for (int off=32; off>=1; off>>=1){
                term += __shfl_xor(term, off, 64);
                cnt  += __shfl_xor(cnt,  off, 64);
            }
            if (lane==0){
                int l0 = lb[0]; int tag0 = l0<0?0:l0;
                float score = st[tag0] + em_s[tag0] + term;
                int li = cnt-1; int ll = lb[li]; int lt = ll<0?0:ll;
                score += et[lt];
                score_s = score;
            }
        }
        // bp ranges: late ranges small (they can't start until the scan finishes)
        const int los[6] = {1,128,256,384,448,480};
        const int his[6] = {128,256,384,448,480,512};
        const int lo = los[wv-2], hi = his[wv-2];

        float trc2[Ln];
        #pragma unroll
        for (int i=0;i<Ln;++i) trc2[i] = trans[i*Ln + j];

        while ((*(volatile int*)&prog_s) * 64 < hi) __builtin_amdgcn_s_sleep(8);

        for (int t = lo; t < hi; ++t){
            const float* ar = &alpha_s[(t-1)*Ln];
            float a[Ln];
            #pragma unroll
            for (int i=0;i<Ln;++i) a[i] = ar[i];
            int bp = lane;
            if (lab2_s[t]){
                float v[Ln];
                #pragma unroll
                for (int i=0;i<Ln;++i) v[i] = a[i] + trc2[i];
                float a0 = fmaxf(fmaxf(v[0],v[1]),v[2]);
                float a1 = fmaxf(fmaxf(v[3],v[4]),v[5]);
                float a2 = fmaxf(fmaxf(v[6],v[7]),v[8]);
                float a3 = fmaxf(fmaxf(v[9],v[10]),v[11]);
                float a4 = fmaxf(fmaxf(v[12],v[13]),v[14]);
                float a5 = fmaxf(fmaxf(v[15],v[16]),v[17]);
                float a6 = fmaxf(fmaxf(v[18],v[19]),v[20]);
                float b0 = fmaxf(fmaxf(a0,a1),a2);
                float b1 = fmaxf(fmaxf(a3,a4),a5);
                float best = fmaxf(fmaxf(b0,b1),a6);
                unsigned bm = 0u;
                #pragma unroll
                for (int i=0;i<Ln;++i) bm |= (v[i]==best) ? (1u<<i) : 0u;
                bp = __ffs(bm) - 1;
            }
            if (act) hist_s[t*Ln + lane] = (unsigned char)bp;
        }
    }
    __syncthreads();   // hist, tag_s, logZ_s, score_s ready

    if (tid < 64){
        unsigned char cur[Ln];
        #pragma unroll
        for (int q=0;q<Ln;++q) cur[q] = (unsigned char)q;
        #pragma unroll
        for (int k=8;k>=1;--k){
            int ta = 8*tid + k;
            if (ta < Tn){
                const unsigned char* hr = &hist_s[ta*Ln];
                #pragma unroll
                for (int q=0;q<Ln;++q) cur[q] = hr[cur[q]];
            }
        }
        #pragma unroll
        for (int q=0;q<Ln;++q) comp_s[tid*Ln+q] = cur[q];
    }
    __syncthreads();
    if (tid==0){
        int cg = tag_s;
        for (int l=63;l>=0;--l){ ent_s[l]=(unsigned char)cg; cg = comp_s[l*Ln+cg]; }
    }
    __syncthreads();
    if (tid < 64){
        int s = ent_s[tid];
        if (tid==63) path_s[Tn-1] = s;
        #pragma unroll
        for (int k=8;k>=1;--k){
            int ta = 8*tid + k;
            if (ta < Tn){ s = hist_s[ta*Ln+s]; path_s[ta-1] = s; }
        }
    }
    __syncthreads();
    float* lg = logits + (size_t)b*Tn*Ln;
    for (int id2=tid; id2<Tn*Ln; id2+=512){
        int t = id2/Ln; int jj = id2 - t*Ln;
        lg[id2] = (lab2_s[t] && path_s[t]==jj) ? 1.0f : 0.0f;
    }
    if (tid==0) (ws+DIFF_OFF)[b] = score_s - logZ_s;
}

// ---------------- finalize: nll = -mean(score - logZ) ----------------
__global__ __launch_bounds__(64) void fin_kernel(const float* __restrict__ ws,
                                                 float* __restrict__ out0)
{
    float v = (ws+DIFF_OFF)[threadIdx.x];
    #pragma unroll
    for (int off=32; off>=1; off>>=1) v += __shfl_xor(v, off, 64);
    if (threadIdx.x==0) out0[0] = -(v * (1.0f/64.0f));
}

extern "C" void kernel_launch(void* const* d_in, const int* in_sizes, int n_in,
                              void* d_out, int out_size, void* d_ws, size_t ws_size,
                              hipStream_t stream)
{
    (void)in_sizes; (void)n_in; (void)out_size; (void)ws_size;
    const float* hidden = (const float*)d_in[0];
    const float* W      = (const float*)d_in[1];
    const float* bias   = (const float*)d_in[2];
    const float* st     = (const float*)d_in[3];
    const float* et     = (const float*)d_in[4];
    const float* trans  = (const float*)d_in[5];
    const int*   labels = (const int*)d_in[6];
    const int*   amask  = (const int*)d_in[7];

    float* out    = (float*)d_out;
    float* nll    = out;
    float* logits = out + 1;
    float* em     = out + 1 + EM_ELEMS;
    float* ws     = (float*)d_ws;

    emis_kernel<<<dim3(Bn*Tn/64), dim3(256), 0, stream>>>(hidden, W, bias, em);
    fused_kernel<<<dim3(Bn), dim3(512), 0, stream>>>(em, labels, amask, st, et, trans, ws, logits);
    fin_kernel<<<dim3(1), dim3(64), 0, stream>>>(ws, nll);
}